// Round 1
// baseline (99.031 us; speedup 1.0000x reference)
//
#include <hip/hip_runtime.h>
#include <math.h>

#define PBLOCK 256
#define MT 1024          // main kernel: 16 waves
#define NSLICE 16        // one j-slice per wave
#define BLOCK 256        // fallback block size

// K1: pack (T, exp(theta)) pairs; zero the scalar accumulator + ticket.
__global__ void surv_prep(const float* __restrict__ theta,
                          const float* __restrict__ T,
                          float2* __restrict__ PE,
                          float* __restrict__ accum, int* __restrict__ ticket,
                          int n) {
    int i = blockIdx.x * PBLOCK + threadIdx.x;
    if (i == 0) { *accum = 0.f; *ticket = 0; }
    if (i < n) {
        PE[i] = make_float2(T[i], expf(theta[i]));
    }
}

// K2: brute-force O(n^2) risk sums.
//  - block b owns i in [b*64, b*64+64): one i per lane.
//  - wave w (0..15) sweeps j-slice [w*n/16, (w+1)*n/16) with wave-uniform
//    float4 loads (2 (T,E) pairs per load; broadcast, L2-resident).
//  - 4 independent accumulators break the dependent-add chain.
//  - cross-wave reduce in LDS; per-block term reduce via shuffles;
//    last block (ticket) finalizes out = -sum/n in-kernel.
__global__ __launch_bounds__(MT) void surv_main(
        const float* __restrict__ theta, const float* __restrict__ T,
        const float* __restrict__ events, const float2* __restrict__ PE,
        float* __restrict__ accum, int* __restrict__ ticket,
        float* __restrict__ out, int n) {
    __shared__ float part[NSLICE][64];
    const int tid  = threadIdx.x;
    const int w    = __builtin_amdgcn_readfirstlane(tid >> 6);  // wave id, uniform
    const int lane = tid & 63;
    const int i    = blockIdx.x * 64 + lane;
    const float Ti = T[i];

    const int slice = n / NSLICE;          // j's per wave
    const int nq    = slice >> 1;          // float4 (2-pair) loads per wave
    const float4* __restrict__ PE4 = (const float4*)PE;
    const int q0 = (w * slice) >> 1;       // uniform float4 start index

    float r0 = 0.f, r1 = 0.f, r2 = 0.f, r3 = 0.f;
    #pragma unroll 4
    for (int q = 0; q < nq; q += 2) {
        float4 a = PE4[q0 + q];
        float4 b = PE4[q0 + q + 1];
        r0 += (a.x >= Ti) ? a.y : 0.f;
        r1 += (a.z >= Ti) ? a.w : 0.f;
        r2 += (b.x >= Ti) ? b.y : 0.f;
        r3 += (b.z >= Ti) ? b.w : 0.f;
    }
    part[w][lane] = (r0 + r1) + (r2 + r3);
    __syncthreads();

    if (w == 0) {
        float risk = part[0][lane];
        #pragma unroll
        for (int ww = 1; ww < NSLICE; ++ww) risk += part[ww][lane];
        float term = (theta[i] - logf(risk)) * events[i];
        #pragma unroll
        for (int off = 32; off > 0; off >>= 1)
            term += __shfl_down(term, off, 64);
        if (lane == 0) {
            atomicAdd(accum, term);
            __threadfence();
            int t = atomicAdd(ticket, 1);
            if (t == (int)gridDim.x - 1) {
                // RMW read at the coherent point (XCD L2s are not cross-coherent;
                // a plain load could be stale).
                float tot = atomicAdd(accum, 0.0f);
                out[0] = -tot / (float)n;
            }
        }
    }
}

// ---------- brute-force fallback (generic n) ----------
__global__ void surv_partial_bf(const float* __restrict__ theta, const float* __restrict__ T,
                                const float* __restrict__ events, float* __restrict__ bsum, int n) {
    __shared__ float red[BLOCK];
    const int tid = threadIdx.x;
    const int i = blockIdx.x * BLOCK + tid;
    float term = 0.f;
    if (i < n) {
        const float Ti = T[i];
        float risk = 0.f;
        for (int j = 0; j < n; ++j)
            risk += (T[j] >= Ti) ? expf(theta[j]) : 0.f;
        term = (theta[i] - logf(risk)) * events[i];
    }
    red[tid] = term;
    __syncthreads();
    for (int s = BLOCK / 2; s > 0; s >>= 1) {
        if (tid < s) red[tid] += red[tid + s];
        __syncthreads();
    }
    if (tid == 0) bsum[blockIdx.x] = red[0];
}

__global__ void surv_final(const float* __restrict__ bsum, float* __restrict__ out,
                           int nblocks, int n) {
    float v = 0.f;
    for (int b = threadIdx.x; b < nblocks; b += 64) v += bsum[b];
    for (int off = 32; off > 0; off >>= 1) v += __shfl_down(v, off, 64);
    if (threadIdx.x == 0) out[0] = -v / (float)n;
}

extern "C" void kernel_launch(void* const* d_in, const int* in_sizes, int n_in,
                              void* d_out, int out_size, void* d_ws, size_t ws_size,
                              hipStream_t stream) {
    const float* theta  = (const float*)d_in[0];
    const float* T      = (const float*)d_in[1];
    const float* events = (const float*)d_in[2];
    float* out = (float*)d_out;
    const int n = in_sizes[0];                  // 16384

    // fast path needs: n % 1024 == 0 (64 i/block, 16 slices, float4-even slices)
    // ws: PE[n] float2, accum float, ticket int
    const size_t need = (size_t)n * 8 + 256;
    const bool fast = (n > 0) && (n % 1024 == 0) && ((size_t)ws_size >= need);

    if (!fast) {
        const int nbi = (n + BLOCK - 1) / BLOCK;
        float* bsum = (float*)d_ws;
        surv_partial_bf<<<nbi, BLOCK, 0, stream>>>(theta, T, events, bsum, n);
        surv_final<<<1, 64, 0, stream>>>(bsum, out, nbi, n);
        return;
    }

    float2* PE     = (float2*)d_ws;
    float*  accum  = (float*)(PE + n);
    int*    ticket = (int*)(accum + 1);

    const int pb = (n + PBLOCK - 1) / PBLOCK;   // 64
    const int mb = n / 64;                      // 256 blocks, 1 per CU

    surv_prep<<<pb, PBLOCK, 0, stream>>>(theta, T, PE, accum, ticket, n);
    surv_main<<<mb, MT, 0, stream>>>(theta, T, events, PE, accum, ticket, out, n);
}